// Round 1
// baseline (1231.770 us; speedup 1.0000x reference)
//
#include <hip/hip_runtime.h>
#include <cmath>

#define D_MODEL 1024
#define NHEADS 16
#define HDIM 64
#define BATCH 2
#define SEQ 2048
#define MROWS (BATCH*SEQ)   // 4096

// ---------------- GEMM: C = A[M=4096,K=1024] * W[K,N=1024] + bias ----------------
// 128x128 block tile, 256 threads, 8x8 microtile (2x2 blocks of 4x4), TK=16.
__global__ __launch_bounds__(256)
void gemm_bias(const float* __restrict__ A, const float* __restrict__ W,
               const float* __restrict__ bias, float* __restrict__ C,
               int store_qkv)
{
    constexpr int K = D_MODEL, N = D_MODEL;
    __shared__ float As[16][132];   // As[k][m], padded: write 2-way, read conflict-free
    __shared__ float Bs[16][132];   // Bs[k][n]

    const int tid = threadIdx.x;
    const int tx = tid & 15;        // col group (owns cols tx*4..+3 and 64+tx*4..+3)
    const int ty = tid >> 4;        // row group
    const int m0 = blockIdx.y * 128;
    const int n0 = blockIdx.x * 128;

    float acc[8][8];
    #pragma unroll
    for (int i = 0; i < 8; ++i)
        #pragma unroll
        for (int j = 0; j < 8; ++j) acc[i][j] = 0.f;

    for (int k0 = 0; k0 < K; k0 += 16) {
        // A tile: 128 rows x 16 k (float4 per thread x2), transpose into As[k][m]
        #pragma unroll
        for (int l = 0; l < 2; ++l) {
            int f4 = l * 256 + tid;          // 0..511
            int row = f4 >> 2;               // 0..127
            int dd = (f4 & 3) << 2;          // 0,4,8,12
            float4 v = *(const float4*)&A[(size_t)(m0 + row) * K + k0 + dd];
            As[dd + 0][row] = v.x;
            As[dd + 1][row] = v.y;
            As[dd + 2][row] = v.z;
            As[dd + 3][row] = v.w;
        }
        // B tile: 16 k x 128 cols
        #pragma unroll
        for (int l = 0; l < 2; ++l) {
            int f4 = l * 256 + tid;
            int row = f4 >> 5;               // 0..15
            int dd = (f4 & 31) << 2;         // 0..124
            *(float4*)&Bs[row][dd] = *(const float4*)&W[(size_t)(k0 + row) * N + n0 + dd];
        }
        __syncthreads();

        #pragma unroll
        for (int kk = 0; kk < 16; ++kk) {
            float4 a0 = *(const float4*)&As[kk][ty * 4];
            float4 a1 = *(const float4*)&As[kk][64 + ty * 4];
            float4 b0 = *(const float4*)&Bs[kk][tx * 4];
            float4 b1 = *(const float4*)&Bs[kk][64 + tx * 4];
            float a[8] = {a0.x, a0.y, a0.z, a0.w, a1.x, a1.y, a1.z, a1.w};
            float b[8] = {b0.x, b0.y, b0.z, b0.w, b1.x, b1.y, b1.z, b1.w};
            #pragma unroll
            for (int i = 0; i < 8; ++i)
                #pragma unroll
                for (int j = 0; j < 8; ++j)
                    acc[i][j] = fmaf(a[i], b[j], acc[i][j]);
        }
        __syncthreads();
    }

    #pragma unroll
    for (int i = 0; i < 8; ++i) {
        int m = m0 + (i < 4 ? ty * 4 + i : 64 + ty * 4 + (i - 4));
        #pragma unroll
        for (int j = 0; j < 8; ++j) {
            int n = n0 + (j < 4 ? tx * 4 + j : 64 + tx * 4 + (j - 4));
            float v = acc[i][j] + bias[n];
            if (store_qkv) {
                // remap [m=b*S+s, n=h*64+d] -> [b,h,s,d]
                int b = m >> 11, s = m & 2047;
                int h = n >> 6, d = n & 63;
                C[((size_t)(b * NHEADS + h) * SEQ + s) * HDIM + d] = v;
            } else {
                C[(size_t)m * N + n] = v;
            }
        }
    }
}

// ---------------- Flash causal attention ----------------
// One block per (bh, 64-row q-tile). 256 threads: rg=tid>>4 owns rows rg*4..+3,
// cgg=tid&15 owns score cols {cgg+16j} and O/V cols cgg*4..+3.
// Row softmax stats via __shfl_xor across the 16 consecutive lanes of a row group.
__global__ __launch_bounds__(256)
void attn_causal(const float* __restrict__ Q, const float* __restrict__ Kg,
                 const float* __restrict__ V, float* __restrict__ Hout)
{
    __shared__ float Qs[64][68];
    __shared__ float Ks[64][68];
    __shared__ float Vs[64][68];
    __shared__ float Ps[64][68];

    const int tid = threadIdx.x;
    const int cgg = tid & 15;
    const int rg  = tid >> 4;
    const int bh = blockIdx.y;                 // b*16+h
    const int q0 = blockIdx.x * 64;
    const float* Qb = Q  + (size_t)bh * SEQ * HDIM;
    const float* Kb = Kg + (size_t)bh * SEQ * HDIM;
    const float* Vb = V  + (size_t)bh * SEQ * HDIM;

    // load Q tile, pre-scaled by 1/sqrt(Dh)
    const float scale = 0.125f;
    #pragma unroll
    for (int l = 0; l < 4; ++l) {
        int f4 = l * 256 + tid;               // 1024 float4s
        int row = f4 >> 4;
        int dd = (f4 & 15) << 2;
        float4 v = *(const float4*)&Qb[(size_t)(q0 + row) * HDIM + dd];
        v.x *= scale; v.y *= scale; v.z *= scale; v.w *= scale;
        *(float4*)&Qs[row][dd] = v;
    }

    float o[4][4];
    #pragma unroll
    for (int i = 0; i < 4; ++i)
        #pragma unroll
        for (int j = 0; j < 4; ++j) o[i][j] = 0.f;
    float mreg[4] = {-INFINITY, -INFINITY, -INFINITY, -INFINITY};
    float lreg[4] = {0.f, 0.f, 0.f, 0.f};
    __syncthreads();

    const int ntiles = q0 / 64 + 1;
    for (int t = 0; t < ntiles; ++t) {
        const int k0 = t * 64;
        #pragma unroll
        for (int l = 0; l < 4; ++l) {
            int f4 = l * 256 + tid;
            int row = f4 >> 4;
            int dd = (f4 & 15) << 2;
            *(float4*)&Ks[row][dd] = *(const float4*)&Kb[(size_t)(k0 + row) * HDIM + dd];
            *(float4*)&Vs[row][dd] = *(const float4*)&Vb[(size_t)(k0 + row) * HDIM + dd];
        }
        __syncthreads();

        // scores: s[i][j] = q[row rg*4+i] . k[col cgg+16j]  (already scaled)
        float s[4][4];
        #pragma unroll
        for (int i = 0; i < 4; ++i)
            #pragma unroll
            for (int j = 0; j < 4; ++j) s[i][j] = 0.f;
        #pragma unroll
        for (int d4 = 0; d4 < 16; ++d4) {
            float4 q4[4], k4[4];
            #pragma unroll
            for (int i = 0; i < 4; ++i) q4[i] = *(const float4*)&Qs[rg * 4 + i][d4 * 4];
            #pragma unroll
            for (int j = 0; j < 4; ++j) k4[j] = *(const float4*)&Ks[cgg + 16 * j][d4 * 4];
            #pragma unroll
            for (int i = 0; i < 4; ++i)
                #pragma unroll
                for (int j = 0; j < 4; ++j)
                    s[i][j] += q4[i].x * k4[j].x + q4[i].y * k4[j].y
                             + q4[i].z * k4[j].z + q4[i].w * k4[j].w;
        }

        // mask + online softmax (row stats across 16-lane group)
        #pragma unroll
        for (int i = 0; i < 4; ++i) {
            const int R = rg * 4 + i;
            const int qidx = q0 + R;
            float mx = -INFINITY;
            #pragma unroll
            for (int j = 0; j < 4; ++j) {
                int kidx = k0 + cgg + 16 * j;
                if (kidx > qidx) s[i][j] = -INFINITY;
                mx = fmaxf(mx, s[i][j]);
            }
            mx = fmaxf(mx, __shfl_xor(mx, 1));
            mx = fmaxf(mx, __shfl_xor(mx, 2));
            mx = fmaxf(mx, __shfl_xor(mx, 4));
            mx = fmaxf(mx, __shfl_xor(mx, 8));
            float mn = fmaxf(mreg[i], mx);      // finite: col k0 is always valid
            float al = __expf(mreg[i] - mn);    // exp(-inf - finite) = 0 on first tile
            float ls = 0.f;
            #pragma unroll
            for (int j = 0; j < 4; ++j) {
                float p = __expf(s[i][j] - mn); // masked -> 0
                Ps[R][cgg + 16 * j] = p;
                ls += p;
            }
            ls += __shfl_xor(ls, 1);
            ls += __shfl_xor(ls, 2);
            ls += __shfl_xor(ls, 4);
            ls += __shfl_xor(ls, 8);
            lreg[i] = lreg[i] * al + ls;
            mreg[i] = mn;
            #pragma unroll
            for (int j = 0; j < 4; ++j) o[i][j] *= al;
        }
        __syncthreads();   // Ps complete (and defensive vs wave-local LDS ordering)

        // O += P . V  (O cols = cgg*4..+3)
        #pragma unroll 4
        for (int k = 0; k < 64; k += 4) {
            float4 p4[4];
            #pragma unroll
            for (int i = 0; i < 4; ++i) p4[i] = *(const float4*)&Ps[rg * 4 + i][k];
            #pragma unroll
            for (int kk = 0; kk < 4; ++kk) {
                float4 v4 = *(const float4*)&Vs[k + kk][cgg * 4];
                #pragma unroll
                for (int i = 0; i < 4; ++i) {
                    float p = (&p4[i].x)[kk];
                    o[i][0] = fmaf(p, v4.x, o[i][0]);
                    o[i][1] = fmaf(p, v4.y, o[i][1]);
                    o[i][2] = fmaf(p, v4.z, o[i][2]);
                    o[i][3] = fmaf(p, v4.w, o[i][3]);
                }
            }
        }
        __syncthreads();   // protect Ks/Vs/Ps before next tile's load
    }

    // epilogue: H[b, s, h*64 + d] layout for the output projection
    const int b = bh >> 4, h = bh & 15;
    #pragma unroll
    for (int i = 0; i < 4; ++i) {
        const int R = rg * 4 + i;
        float linv = 1.f / lreg[i];
        float4 v;
        v.x = o[i][0] * linv; v.y = o[i][1] * linv;
        v.z = o[i][2] * linv; v.w = o[i][3] * linv;
        *(float4*)&Hout[((size_t)(b * SEQ + q0 + R)) * D_MODEL + h * HDIM + cgg * 4] = v;
    }
}

extern "C" void kernel_launch(void* const* d_in, const int* in_sizes, int n_in,
                              void* d_out, int out_size, void* d_ws, size_t ws_size,
                              hipStream_t stream)
{
    (void)in_sizes; (void)n_in; (void)out_size; (void)ws_size;
    const float* x  = (const float*)d_in[0];
    const float* Wq = (const float*)d_in[1];
    const float* bq = (const float*)d_in[2];
    const float* Wk = (const float*)d_in[3];
    const float* bk = (const float*)d_in[4];
    const float* Wv = (const float*)d_in[5];
    const float* bv = (const float*)d_in[6];
    const float* Wo = (const float*)d_in[7];
    const float* bo = (const float*)d_in[8];
    float* out = (float*)d_out;

    const size_t elems = (size_t)MROWS * D_MODEL;   // 4 Mi floats = 16 MB each
    float* Qb = (float*)d_ws;
    float* Kb = Qb + elems;
    float* Vb = Kb + elems;
    float* Hb = Vb + elems;                          // total 64 MB workspace

    dim3 gemm_grid(D_MODEL / 128, MROWS / 128);      // (8, 32)
    gemm_bias<<<gemm_grid, 256, 0, stream>>>(x, Wq, bq, Qb, 1);
    gemm_bias<<<gemm_grid, 256, 0, stream>>>(x, Wk, bk, Kb, 1);
    gemm_bias<<<gemm_grid, 256, 0, stream>>>(x, Wv, bv, Vb, 1);

    attn_causal<<<dim3(SEQ / 64, BATCH * NHEADS), 256, 0, stream>>>(Qb, Kb, Vb, Hb);

    gemm_bias<<<gemm_grid, 256, 0, stream>>>(Hb, Wo, bo, out, 0);
}

// Round 2
// 319.143 us; speedup vs baseline: 3.8596x; 3.8596x over previous
//
#include <hip/hip_runtime.h>
#include <cmath>

#define D_MODEL 1024
#define NHEADS 16
#define HDIM 64
#define BATCH 2
#define SEQ 2048
#define MROWS (BATCH*SEQ)   // 4096
#define KDIM 1024

typedef unsigned short ushort_t;
typedef unsigned int uint32;
typedef __attribute__((ext_vector_type(8))) short short8;
typedef __attribute__((ext_vector_type(4))) float floatx4;

__device__ __forceinline__ ushort_t f2bf(float x) {
    union { float f; uint32 u; } v; v.f = x;
    uint32 r = v.u + 0x7FFFu + ((v.u >> 16) & 1u);   // round-to-nearest-even-ish
    return (ushort_t)(r >> 16);
}

__device__ __forceinline__ void glds16(const void* g, void* l) {
    __builtin_amdgcn_global_load_lds(
        (const __attribute__((address_space(1))) void*)g,
        (__attribute__((address_space(3))) void*)l, 16, 0, 0);
}

// ---------------- fp32 -> bf16 elementwise (x) ----------------
__global__ __launch_bounds__(256)
void cvt_bf16(const float* __restrict__ src, ushort_t* __restrict__ dst)
{
    size_t i = ((size_t)blockIdx.x * 256 + threadIdx.x) * 4;
    float4 v = *(const float4*)(src + i);
    uint32 a = (uint32)f2bf(v.x) | ((uint32)f2bf(v.y) << 16);
    uint32 b = (uint32)f2bf(v.z) | ((uint32)f2bf(v.w) << 16);
    *(uint2*)(dst + i) = make_uint2(a, b);
}

// ---------------- fp32 W[k][n] -> bf16 Wt[n][k] (transpose) ----------------
__global__ __launch_bounds__(256)
void cvt_transpose_w(const float* __restrict__ W0, const float* __restrict__ W1,
                     const float* __restrict__ W2, const float* __restrict__ W3,
                     ushort_t* __restrict__ WtQKV, ushort_t* __restrict__ WtO)
{
    __shared__ float tl[32][33];
    const int z = blockIdx.z;
    const float* W = (z == 0) ? W0 : (z == 1) ? W1 : (z == 2) ? W2 : W3;
    ushort_t* out = (z < 3) ? (WtQKV + (size_t)z * D_MODEL * KDIM) : WtO;
    const int k0 = blockIdx.x * 32, n0 = blockIdx.y * 32;
    const int tx = threadIdx.x & 31, ty = threadIdx.x >> 5;
    #pragma unroll
    for (int i = 0; i < 4; ++i)
        tl[ty + i * 8][tx] = W[(size_t)(k0 + ty + i * 8) * D_MODEL + n0 + tx];
    __syncthreads();
    #pragma unroll
    for (int i = 0; i < 4; ++i)
        out[(size_t)(n0 + ty + i * 8) * KDIM + k0 + tx] = f2bf(tl[tx][ty + i * 8]);
}

// ---------------- bf16 MFMA GEMM: C = A[4096,1024] * Bt^T + bias ----------------
// A row-major [M][K] bf16; Bt row-major [N][K] bf16 (i.e. W transposed).
// 128x128 block tile, BK=64, 4 waves (2x2 of 64x64), 16x16x32 MFMA.
// LDS staged via global_load_lds width-16 with XOR chunk swizzle:
//   chunk (row, kc) stored at position kc ^ (row&7) within the row's 8 chunks.
__global__ __launch_bounds__(256)
void gemm_mfma(const ushort_t* __restrict__ A, const ushort_t* __restrict__ Bt,
               const float* __restrict__ b0, const float* __restrict__ b1,
               const float* __restrict__ b2, float* __restrict__ Cf,
               ushort_t* __restrict__ Qb, ushort_t* __restrict__ Kb,
               ushort_t* __restrict__ Vb, int mode)
{
    __shared__ ushort_t As[128 * 64];   // 16 KB
    __shared__ ushort_t Bs[128 * 64];   // 16 KB

    const int tid = threadIdx.x;
    const int w = tid >> 6, lane = tid & 63;
    const int quad = lane >> 4, col = lane & 15;
    const int m0 = blockIdx.y * 128, n0 = blockIdx.x * 128;
    const int mbase = (w & 1) * 64, nbase = (w >> 1) * 64;

    floatx4 zero = {0.f, 0.f, 0.f, 0.f};
    floatx4 acc[4][4];
    #pragma unroll
    for (int i = 0; i < 4; ++i)
        #pragma unroll
        for (int j = 0; j < 4; ++j) acc[i][j] = zero;

    #pragma unroll 1
    for (int k0 = 0; k0 < KDIM; k0 += 64) {
        #pragma unroll
        for (int i = 0; i < 4; ++i) {
            int c = (w * 4 + i) * 64 + lane;
            int row = c >> 3;
            int kc = (c & 7) ^ (row & 7);
            glds16(A  + (size_t)(m0 + row) * KDIM + k0 + kc * 8, As + (w * 4 + i) * 512);
            glds16(Bt + (size_t)(n0 + row) * KDIM + k0 + kc * 8, Bs + (w * 4 + i) * 512);
        }
        __syncthreads();
        #pragma unroll
        for (int ks = 0; ks < 2; ++ks) {
            short8 af[4], bfr[4];
            const int kc = ks * 4 + quad;
            #pragma unroll
            for (int mt = 0; mt < 4; ++mt) {
                int r = mbase + mt * 16 + col;
                af[mt] = *(const short8*)(As + ((size_t)r * 8 + (kc ^ (r & 7))) * 8);
            }
            #pragma unroll
            for (int nt = 0; nt < 4; ++nt) {
                int r = nbase + nt * 16 + col;
                bfr[nt] = *(const short8*)(Bs + ((size_t)r * 8 + (kc ^ (r & 7))) * 8);
            }
            #pragma unroll
            for (int mt = 0; mt < 4; ++mt)
                #pragma unroll
                for (int nt = 0; nt < 4; ++nt)
                    acc[mt][nt] = __builtin_amdgcn_mfma_f32_16x16x32_bf16(
                        af[mt], bfr[nt], acc[mt][nt], 0, 0, 0);
        }
        __syncthreads();
    }

    if (mode == 0) {
        // fp32 store C[m][n] + bias (output projection)
        #pragma unroll
        for (int mt = 0; mt < 4; ++mt)
            #pragma unroll
            for (int nt = 0; nt < 4; ++nt) {
                int n = n0 + nbase + nt * 16 + col;
                float bb = b0[n];
                #pragma unroll
                for (int r = 0; r < 4; ++r) {
                    int m = m0 + mbase + mt * 16 + quad * 4 + r;
                    Cf[(size_t)m * D_MODEL + n] = acc[mt][nt][r] + bb;
                }
            }
    } else {
        // bf16 QKV store in [b,h,s,d]
        const int which = n0 >> 10;
        const float* bp = (which == 0) ? b0 : (which == 1) ? b1 : b2;
        ushort_t* outp  = (which == 0) ? Qb : (which == 1) ? Kb : Vb;
        #pragma unroll
        for (int mt = 0; mt < 4; ++mt)
            #pragma unroll
            for (int nt = 0; nt < 4; ++nt) {
                int ng = n0 + nbase + nt * 16 + col;
                int nn = ng & 1023;
                float bb = bp[nn];
                int h = nn >> 6, d = nn & 63;
                #pragma unroll
                for (int r = 0; r < 4; ++r) {
                    int m = m0 + mbase + mt * 16 + quad * 4 + r;
                    int b = m >> 11, s = m & 2047;
                    outp[((size_t)(b * NHEADS + h) * SEQ + s) * HDIM + d] =
                        f2bf(acc[mt][nt][r] + bb);
                }
            }
    }
}

// ---------------- flash causal attention, bf16 MFMA ----------------
// Block = 4 waves; wave w owns q-rows [w*16, w*16+16) of a 64-row q-tile.
// Q/K staged via global_load_lds (swizzled); V transposed into Vt[d][kpos]
// (stride 72 -> conflict-free b128 B-frags); P round-trips LDS as bf16
// (wave-private rows, same-wave DS ordering, no extra barrier).
__global__ __launch_bounds__(256)
void attn_mfma(const ushort_t* __restrict__ Q, const ushort_t* __restrict__ K,
               const ushort_t* __restrict__ V, ushort_t* __restrict__ H)
{
    __shared__ ushort_t Qs[64 * 64];    // swizzled chunks
    __shared__ ushort_t Ks[64 * 64];
    __shared__ ushort_t Vt[64 * 72];    // [d][kpos], stride 72
    __shared__ ushort_t Ps[64 * 72];    // [qrow][kpos], stride 72

    const int tid = threadIdx.x;
    const int w = tid >> 6, lane = tid & 63;
    const int quad = lane >> 4, col = lane & 15;
    const int bh = blockIdx.y, qt = blockIdx.x;
    const int q0 = qt * 64;
    const size_t base = (size_t)bh * SEQ * HDIM;

    // stage Q tile once
    #pragma unroll
    for (int i = 0; i < 2; ++i) {
        int c = (w * 2 + i) * 64 + lane;
        int row = c >> 3, kc = (c & 7) ^ (row & 7);
        glds16(Q + base + (size_t)(q0 + row) * HDIM + kc * 8, Qs + (w * 2 + i) * 512);
    }

    floatx4 zero = {0.f, 0.f, 0.f, 0.f};
    floatx4 o[4];
    #pragma unroll
    for (int j = 0; j < 4; ++j) o[j] = zero;
    float mreg[4] = {-INFINITY, -INFINITY, -INFINITY, -INFINITY};
    float lreg[4] = {0.f, 0.f, 0.f, 0.f};
    const float SCALE = 0.125f * 1.44269504f;   // fold 1/sqrt(64) into exp2

    for (int t = 0; t <= qt; ++t) {
        const int k0 = t * 64;
        #pragma unroll
        for (int i = 0; i < 2; ++i) {
            int c = (w * 2 + i) * 64 + lane;
            int row = c >> 3, kc = (c & 7) ^ (row & 7);
            glds16(K + base + (size_t)(k0 + row) * HDIM + kc * 8, Ks + (w * 2 + i) * 512);
        }
        {   // V transpose: wave w fills d-rows [w*16, w*16+16)
            const ushort_t* vg = V + base + (size_t)(k0 + lane) * HDIM + w * 16;
            union { uint4 q[2]; ushort_t s[16]; } vv;
            vv.q[0] = *(const uint4*)vg;
            vv.q[1] = *(const uint4*)(vg + 8);
            #pragma unroll
            for (int i = 0; i < 16; ++i)
                Vt[(size_t)(w * 16 + i) * 72 + lane] = vv.s[i];
        }
        __syncthreads();

        // S = Q K^T for this wave's 16 rows x 64 kpos
        floatx4 sc[4];
        #pragma unroll
        for (int j = 0; j < 4; ++j) sc[j] = zero;
        #pragma unroll
        for (int ks = 0; ks < 2; ++ks) {
            const int kc = ks * 4 + quad;
            const int rq = w * 16 + col;
            short8 aq = *(const short8*)(Qs + ((size_t)rq * 8 + (kc ^ (rq & 7))) * 8);
            #pragma unroll
            for (int j = 0; j < 4; ++j) {
                int rk = j * 16 + col;
                short8 bk = *(const short8*)(Ks + ((size_t)rk * 8 + (kc ^ (rk & 7))) * 8);
                sc[j] = __builtin_amdgcn_mfma_f32_16x16x32_bf16(aq, bk, sc[j], 0, 0, 0);
            }
        }

        // online softmax; C-layout row = quad*4+r, col = lane&15
        const bool diag = (t == qt);
        #pragma unroll
        for (int r = 0; r < 4; ++r) {
            const int rloc = w * 16 + quad * 4 + r;
            float s0 = sc[0][r] * SCALE, s1 = sc[1][r] * SCALE;
            float s2 = sc[2][r] * SCALE, s3 = sc[3][r] * SCALE;
            if (diag) {
                if (col      > rloc) s0 = -INFINITY;
                if (col + 16 > rloc) s1 = -INFINITY;
                if (col + 32 > rloc) s2 = -INFINITY;
                if (col + 48 > rloc) s3 = -INFINITY;
            }
            float mx = fmaxf(fmaxf(s0, s1), fmaxf(s2, s3));
            mx = fmaxf(mx, __shfl_xor(mx, 1));
            mx = fmaxf(mx, __shfl_xor(mx, 2));
            mx = fmaxf(mx, __shfl_xor(mx, 4));
            mx = fmaxf(mx, __shfl_xor(mx, 8));
            float mn = fmaxf(mreg[r], mx);
            float alpha = exp2f(mreg[r] - mn);
            mreg[r] = mn;
            float p0 = exp2f(s0 - mn), p1 = exp2f(s1 - mn);
            float p2 = exp2f(s2 - mn), p3 = exp2f(s3 - mn);
            float ls = p0 + p1 + p2 + p3;
            ls += __shfl_xor(ls, 1);
            ls += __shfl_xor(ls, 2);
            ls += __shfl_xor(ls, 4);
            ls += __shfl_xor(ls, 8);
            lreg[r] = lreg[r] * alpha + ls;
            size_t pb = (size_t)rloc * 72 + col;
            Ps[pb]      = f2bf(p0);
            Ps[pb + 16] = f2bf(p1);
            Ps[pb + 32] = f2bf(p2);
            Ps[pb + 48] = f2bf(p3);
            o[0][r] *= alpha; o[1][r] *= alpha; o[2][r] *= alpha; o[3][r] *= alpha;
        }

        // O += P V   (A-frag from Ps, B-frag from Vt)
        #pragma unroll
        for (int ks = 0; ks < 2; ++ks) {
            short8 ap = *(const short8*)(Ps + (size_t)(w * 16 + col) * 72 + ks * 32 + quad * 8);
            #pragma unroll
            for (int j = 0; j < 4; ++j) {
                short8 bv = *(const short8*)(Vt + (size_t)(j * 16 + col) * 72 + ks * 32 + quad * 8);
                o[j] = __builtin_amdgcn_mfma_f32_16x16x32_bf16(ap, bv, o[j], 0, 0, 0);
            }
        }
        __syncthreads();
    }

    // epilogue: H[b, s, h*64+d] bf16
    const int b = bh >> 4, h = bh & 15;
    #pragma unroll
    for (int r = 0; r < 4; ++r) {
        float linv = 1.f / lreg[r];
        int s = q0 + w * 16 + quad * 4 + r;
        #pragma unroll
        for (int j = 0; j < 4; ++j)
            H[(size_t)(b * SEQ + s) * D_MODEL + h * HDIM + j * 16 + col] =
                f2bf(o[j][r] * linv);
    }
}

extern "C" void kernel_launch(void* const* d_in, const int* in_sizes, int n_in,
                              void* d_out, int out_size, void* d_ws, size_t ws_size,
                              hipStream_t stream)
{
    (void)in_sizes; (void)n_in; (void)out_size; (void)ws_size;
    const float* x  = (const float*)d_in[0];
    const float* Wq = (const float*)d_in[1];
    const float* bq = (const float*)d_in[2];
    const float* Wk = (const float*)d_in[3];
    const float* bk = (const float*)d_in[4];
    const float* Wv = (const float*)d_in[5];
    const float* bv = (const float*)d_in[6];
    const float* Wo = (const float*)d_in[7];
    const float* bo = (const float*)d_in[8];

    const size_t E = (size_t)MROWS * D_MODEL;        // 4 Mi elements
    ushort_t* xb    = (ushort_t*)d_ws;               // [4096][1024] bf16
    ushort_t* WtQKV = xb + E;                        // [3072][1024] bf16
    ushort_t* WtO   = WtQKV + 3 * (size_t)D_MODEL * KDIM;
    ushort_t* Qb    = WtO + (size_t)D_MODEL * KDIM;  // [b,h,s,d] bf16
    ushort_t* Kb    = Qb + E;
    ushort_t* Vb    = Kb + E;
    ushort_t* Hb    = Vb + E;                        // [4096][1024] bf16
    // total: (4+3+1+4*4) Mi * 2 B = 48 MB

    cvt_bf16<<<dim3(MROWS * D_MODEL / 1024), 256, 0, stream>>>(x, xb);
    cvt_transpose_w<<<dim3(32, 32, 4), 256, 0, stream>>>(Wq, Wk, Wv, Wo, WtQKV, WtO);
    gemm_mfma<<<dim3(24, 32), 256, 0, stream>>>(xb, WtQKV, bq, bk, bv,
                                                nullptr, Qb, Kb, Vb, 1);
    attn_mfma<<<dim3(SEQ / 64, BATCH * NHEADS), 256, 0, stream>>>(Qb, Kb, Vb, Hb);
    gemm_mfma<<<dim3(8, 32), 256, 0, stream>>>(Hb, WtO, bo, nullptr, nullptr,
                                               (float*)d_out, nullptr, nullptr, nullptr, 0);
}

// Round 4
// 226.982 us; speedup vs baseline: 5.4267x; 1.4060x over previous
//
#include <hip/hip_runtime.h>
#include <hip/hip_bf16.h>
#include <cmath>

#define D_MODEL 1024
#define NHEADS 16
#define HDIM 64
#define BATCH 2
#define SEQ 2048
#define MROWS (BATCH*SEQ)   // 4096
#define KDIM 1024

typedef unsigned short ushort_t;
typedef unsigned int uint32;
typedef __attribute__((ext_vector_type(8))) short short8;
typedef __attribute__((ext_vector_type(4))) float floatx4;

#define QSCALE 0.1803368801111204f   /* 0.125 * log2(e): scores land in exp2 domain */
#define EXP2F(x) __builtin_amdgcn_exp2f(x)

__device__ __forceinline__ ushort_t f2bf(float x) {
    union { float f; uint32 u; } v; v.f = x;
    uint32 r = v.u + 0x7FFFu + ((v.u >> 16) & 1u);
    return (ushort_t)(r >> 16);
}

__device__ __forceinline__ uint32 pkbf(float a, float b) {
    union { __hip_bfloat162 h2; uint32 u; } v;
    v.h2 = __float22bfloat162_rn(make_float2(a, b));
    return v.u;
}

__device__ __forceinline__ void glds16(const void* g, void* l) {
    __builtin_amdgcn_global_load_lds(
        (const __attribute__((address_space(1))) void*)g,
        (__attribute__((address_space(3))) void*)l, 16, 0, 0);
}

// ---------------- fp32 -> bf16 elementwise (x) ----------------
__global__ __launch_bounds__(256)
void cvt_bf16(const float* __restrict__ src, ushort_t* __restrict__ dst)
{
    size_t i = ((size_t)blockIdx.x * 256 + threadIdx.x) * 4;
    float4 v = *(const float4*)(src + i);
    uint2 o;
    o.x = pkbf(v.x, v.y);
    o.y = pkbf(v.z, v.w);
    *(uint2*)(dst + i) = o;
}

// ---------------- fp32 W[k][n] -> bf16 Wt[n][k] (transpose) ----------------
__global__ __launch_bounds__(256)
void cvt_transpose_w(const float* __restrict__ W0, const float* __restrict__ W1,
                     const float* __restrict__ W2, const float* __restrict__ W3,
                     ushort_t* __restrict__ WtQKV, ushort_t* __restrict__ WtO)
{
    __shared__ float tl[32][33];
    const int z = blockIdx.z;
    const float* W = (z == 0) ? W0 : (z == 1) ? W1 : (z == 2) ? W2 : W3;
    ushort_t* out = (z < 3) ? (WtQKV + (size_t)z * D_MODEL * KDIM) : WtO;
    const int k0 = blockIdx.x * 32, n0 = blockIdx.y * 32;
    const int tx = threadIdx.x & 31, ty = threadIdx.x >> 5;
    #pragma unroll
    for (int i = 0; i < 4; ++i)
        tl[ty + i * 8][tx] = W[(size_t)(k0 + ty + i * 8) * D_MODEL + n0 + tx];
    __syncthreads();
    #pragma unroll
    for (int i = 0; i < 4; ++i)
        out[(size_t)(n0 + ty + i * 8) * KDIM + k0 + tx] = f2bf(tl[tx][ty + i * 8]);
}

// ---------------- bf16 MFMA GEMM: C = A[4096,1024] * Bt^T + bias ----------------
// mode 0: fp32 C[m][n] (+bias) store.   mode 1: QKV epilogue:
//   Q -> bf16 [b,h,s,d] scaled by QSCALE; K -> bf16 [b,h,s,d]; V -> bf16 [b,h,d,s].
__global__ __launch_bounds__(256)
void gemm_mfma(const ushort_t* __restrict__ A, const ushort_t* __restrict__ Bt,
               const float* __restrict__ b0, const float* __restrict__ b1,
               const float* __restrict__ b2, float* __restrict__ Cf,
               ushort_t* __restrict__ Qb, ushort_t* __restrict__ Kb,
               ushort_t* __restrict__ Vb, int mode)
{
    __shared__ ushort_t As[128 * 64];   // 16 KB
    __shared__ ushort_t Bs[128 * 64];   // 16 KB

    const int tid = threadIdx.x;
    const int w = tid >> 6, lane = tid & 63;
    const int quad = lane >> 4, col = lane & 15;
    const int m0 = blockIdx.y * 128, n0 = blockIdx.x * 128;
    const int mbase = (w & 1) * 64, nbase = (w >> 1) * 64;

    floatx4 zero = {0.f, 0.f, 0.f, 0.f};
    floatx4 acc[4][4];
    #pragma unroll
    for (int i = 0; i < 4; ++i)
        #pragma unroll
        for (int j = 0; j < 4; ++j) acc[i][j] = zero;

    #pragma unroll 1
    for (int k0 = 0; k0 < KDIM; k0 += 64) {
        #pragma unroll
        for (int i = 0; i < 4; ++i) {
            int c = (w * 4 + i) * 64 + lane;
            int row = c >> 3;
            int kc = (c & 7) ^ (row & 7);
            glds16(A  + (size_t)(m0 + row) * KDIM + k0 + kc * 8, As + (w * 4 + i) * 512);
            glds16(Bt + (size_t)(n0 + row) * KDIM + k0 + kc * 8, Bs + (w * 4 + i) * 512);
        }
        __syncthreads();
        #pragma unroll
        for (int ks = 0; ks < 2; ++ks) {
            short8 af[4], bfr[4];
            const int kc = ks * 4 + quad;
            #pragma unroll
            for (int mt = 0; mt < 4; ++mt) {
                int r = mbase + mt * 16 + col;
                af[mt] = *(const short8*)(As + ((size_t)r * 8 + (kc ^ (r & 7))) * 8);
            }
            #pragma unroll
            for (int nt = 0; nt < 4; ++nt) {
                int r = nbase + nt * 16 + col;
                bfr[nt] = *(const short8*)(Bs + ((size_t)r * 8 + (kc ^ (r & 7))) * 8);
            }
            #pragma unroll
            for (int mt = 0; mt < 4; ++mt)
                #pragma unroll
                for (int nt = 0; nt < 4; ++nt)
                    acc[mt][nt] = __builtin_amdgcn_mfma_f32_16x16x32_bf16(
                        af[mt], bfr[nt], acc[mt][nt], 0, 0, 0);
        }
        __syncthreads();
    }

    if (mode == 0) {
        #pragma unroll
        for (int mt = 0; mt < 4; ++mt)
            #pragma unroll
            for (int nt = 0; nt < 4; ++nt) {
                int n = n0 + nbase + nt * 16 + col;
                float bb = b0[n];
                #pragma unroll
                for (int r = 0; r < 4; ++r) {
                    int m = m0 + mbase + mt * 16 + quad * 4 + r;
                    Cf[(size_t)m * D_MODEL + n] = acc[mt][nt][r] + bb;
                }
            }
    } else {
        const int which = n0 >> 10;
        const float* bp = (which == 0) ? b0 : (which == 1) ? b1 : b2;
        if (which < 2) {
            // Q (scaled) / K -> [b,h,s,d]
            ushort_t* outp = (which == 0) ? Qb : Kb;
            const float scl = (which == 0) ? QSCALE : 1.0f;
            #pragma unroll
            for (int mt = 0; mt < 4; ++mt)
                #pragma unroll
                for (int nt = 0; nt < 4; ++nt) {
                    int nn = (n0 + nbase + nt * 16 + col) & 1023;
                    float bb = bp[nn];
                    int h = nn >> 6, d = nn & 63;
                    #pragma unroll
                    for (int r = 0; r < 4; ++r) {
                        int m = m0 + mbase + mt * 16 + quad * 4 + r;
                        int b = m >> 11, s = m & 2047;
                        outp[((size_t)(b * NHEADS + h) * SEQ + s) * HDIM + d] =
                            f2bf((acc[mt][nt][r] + bb) * scl);
                    }
                }
        } else {
            // V -> [b,h,d,s] (transposed for attention PV), packed 8B stores
            #pragma unroll
            for (int mt = 0; mt < 4; ++mt)
                #pragma unroll
                for (int nt = 0; nt < 4; ++nt) {
                    int nn = (n0 + nbase + nt * 16 + col) & 1023;
                    float bb = bp[nn];
                    int h = nn >> 6, d = nn & 63;
                    int mb = m0 + mbase + mt * 16 + quad * 4;
                    int b = mb >> 11, s = mb & 2047;
                    uint2 pw;
                    pw.x = pkbf(acc[mt][nt][0] + bb, acc[mt][nt][1] + bb);
                    pw.y = pkbf(acc[mt][nt][2] + bb, acc[mt][nt][3] + bb);
                    *(uint2*)(Vb + ((size_t)(b * NHEADS + h) * HDIM + d) * SEQ + s) = pw;
                }
        }
    }
}

// ---------------- flash causal attention, bf16 MFMA, S^T scheme ----------------
// Block = 4 waves, 64 q-rows; wave w owns q-rows [w*16, w*16+16) as MFMA COLUMNS.
// S^T = K . Q^T  -> lane holds 16 kpos for ONE q (col): row stats = 15 local ops
// + 2 shfls. PV as O^T = V^T . P^T with A=Vt (global [b,h,d,s]), B=Ps (LDS).
// Ps aliases Qs (Q frags hoisted to regs). Heavy q-tiles launch first.
__global__ __launch_bounds__(256)
void attn_mfma(const ushort_t* __restrict__ Q, const ushort_t* __restrict__ K,
               const ushort_t* __restrict__ Vt, ushort_t* __restrict__ H)
{
    __shared__ ushort_t Qs[64 * 64];    // becomes Ps after Q frags are hoisted
    __shared__ ushort_t Ks[64 * 64];
    __shared__ ushort_t Vs[64 * 64];    // staged from Vt global: rows = d
    ushort_t* Ps = Qs;

    const int tid = threadIdx.x;
    const int w = tid >> 6, lane = tid & 63;
    const int quad = lane >> 4, col = lane & 15;
    const int bh = blockIdx.y;
    const int qt = gridDim.x - 1 - blockIdx.x;   // heavy blocks first
    const int q0 = qt * 64;
    const size_t base = (size_t)bh * SEQ * HDIM;

    // stage Q tile (rows=s, 64 d), then hoist this wave's B-fragments to regs
    #pragma unroll
    for (int i = 0; i < 2; ++i) {
        int c = (w * 2 + i) * 64 + lane;
        int row = c >> 3, kc = (c & 7) ^ (row & 7);
        glds16(Q + base + (size_t)(q0 + row) * HDIM + kc * 8, Qs + (w * 2 + i) * 512);
    }
    __syncthreads();
    short8 bq[2];
    {
        const int rq = w * 16 + col;
        #pragma unroll
        for (int ks = 0; ks < 2; ++ks) {
            int kc = ks * 4 + quad;
            bq[ks] = *(const short8*)(Qs + ((size_t)rq * 8 + (kc ^ (rq & 7))) * 8);
        }
    }

    floatx4 zero = {0.f, 0.f, 0.f, 0.f};
    floatx4 o[4];
    #pragma unroll
    for (int j = 0; j < 4; ++j) o[j] = zero;
    float mreg = -INFINITY, lreg = 0.f;
    const int qloc = w * 16 + col;               // this lane's q row (local)
    const int rq = w * 16 + col;                 // Ps row

    #pragma unroll 1
    for (int t = 0; t <= qt; ++t) {
        const int k0 = t * 64;
        #pragma unroll
        for (int i = 0; i < 2; ++i) {
            int c = (w * 2 + i) * 64 + lane;
            int row = c >> 3, kc = (c & 7) ^ (row & 7);
            glds16(K  + base + (size_t)(k0 + row) * HDIM + kc * 8, Ks + (w * 2 + i) * 512);
            glds16(Vt + base + (size_t)row * SEQ + k0 + kc * 8,    Vs + (w * 2 + i) * 512);
        }
        __syncthreads();

        // S^T[kpos][q]: sc[j] reg r -> kpos = j*16+quad*4+r, q = col (wave-local)
        floatx4 sc[4];
        #pragma unroll
        for (int j = 0; j < 4; ++j) sc[j] = zero;
        #pragma unroll
        for (int ks = 0; ks < 2; ++ks) {
            const int kc = ks * 4 + quad;
            #pragma unroll
            for (int j = 0; j < 4; ++j) {
                int rk = j * 16 + col;
                short8 ak = *(const short8*)(Ks + ((size_t)rk * 8 + (kc ^ (rk & 7))) * 8);
                sc[j] = __builtin_amdgcn_mfma_f32_16x16x32_bf16(ak, bq[ks], sc[j], 0, 0, 0);
            }
        }

        // causal mask (diagonal tile only; wave-uniform branch)
        if (t == qt) {
            #pragma unroll
            for (int j = 0; j < 4; ++j)
                #pragma unroll
                for (int r = 0; r < 4; ++r)
                    if (j * 16 + quad * 4 + r > qloc) sc[j][r] = -INFINITY;
        }

        // online softmax: local max/sum over 16 regs + 2 shfls across quads
        float mx = -INFINITY;
        #pragma unroll
        for (int j = 0; j < 4; ++j) {
            mx = fmaxf(mx, fmaxf(fmaxf(sc[j][0], sc[j][1]), fmaxf(sc[j][2], sc[j][3])));
        }
        mx = fmaxf(mx, __shfl_xor(mx, 16));
        mx = fmaxf(mx, __shfl_xor(mx, 32));
        float mn = fmaxf(mreg, mx);
        float alpha = EXP2F(mreg - mn);
        mreg = mn;

        float ls = 0.f;
        #pragma unroll
        for (int j = 0; j < 4; ++j) {
            float p0 = EXP2F(sc[j][0] - mn);
            float p1 = EXP2F(sc[j][1] - mn);
            float p2 = EXP2F(sc[j][2] - mn);
            float p3 = EXP2F(sc[j][3] - mn);
            ls += (p0 + p1) + (p2 + p3);
            uint2 pw;
            pw.x = pkbf(p0, p1);
            pw.y = pkbf(p2, p3);
            int c = 2 * j + (quad >> 1);
            *(uint2*)(Ps + ((size_t)rq * 8 + (c ^ (rq & 7))) * 8 + (quad & 1) * 4) = pw;
        }
        ls += __shfl_xor(ls, 16);
        ls += __shfl_xor(ls, 32);
        lreg = lreg * alpha + ls;
        #pragma unroll
        for (int j = 0; j < 4; ++j) {
            o[j][0] *= alpha; o[j][1] *= alpha; o[j][2] *= alpha; o[j][3] *= alpha;
        }

        // O^T += V^T . P^T : A-frag rows = d (Vs), B-frag rows = q (Ps, own wave)
        #pragma unroll
        for (int ks = 0; ks < 2; ++ks) {
            const int kc = ks * 4 + quad;
            short8 bp = *(const short8*)(Ps + ((size_t)rq * 8 + (kc ^ (rq & 7))) * 8);
            #pragma unroll
            for (int j = 0; j < 4; ++j) {
                int rv = j * 16 + col;
                short8 av = *(const short8*)(Vs + ((size_t)rv * 8 + (kc ^ (rv & 7))) * 8);
                o[j] = __builtin_amdgcn_mfma_f32_16x16x32_bf16(av, bp, o[j], 0, 0, 0);
            }
        }
        __syncthreads();
    }

    // epilogue: lane owns q row s = q0+qloc, d = j*16+quad*4+r; H[b,s,h*64+d]
    const int b = bh >> 4, h = bh & 15;
    const float linv = 1.f / lreg;
    const size_t rowb = ((size_t)(b * SEQ + q0 + qloc)) * D_MODEL + h * HDIM;
    #pragma unroll
    for (int j = 0; j < 4; ++j) {
        uint2 pw;
        pw.x = pkbf(o[j][0] * linv, o[j][1] * linv);
        pw.y = pkbf(o[j][2] * linv, o[j][3] * linv);
        *(uint2*)(H + rowb + j * 16 + quad * 4) = pw;
    }
}

extern "C" void kernel_launch(void* const* d_in, const int* in_sizes, int n_in,
                              void* d_out, int out_size, void* d_ws, size_t ws_size,
                              hipStream_t stream)
{
    (void)in_sizes; (void)n_in; (void)out_size; (void)ws_size;
    const float* x  = (const float*)d_in[0];
    const float* Wq = (const float*)d_in[1];
    const float* bq = (const float*)d_in[2];
    const float* Wk = (const float*)d_in[3];
    const float* bk = (const float*)d_in[4];
    const float* Wv = (const float*)d_in[5];
    const float* bv = (const float*)d_in[6];
    const float* Wo = (const float*)d_in[7];
    const float* bo = (const float*)d_in[8];

    const size_t E = (size_t)MROWS * D_MODEL;
    ushort_t* xb    = (ushort_t*)d_ws;               // [4096][1024] bf16
    ushort_t* WtQKV = xb + E;                        // [3072][1024] bf16
    ushort_t* WtO   = WtQKV + 3 * (size_t)D_MODEL * KDIM;
    ushort_t* Qb    = WtO + (size_t)D_MODEL * KDIM;  // [b,h,s,d] bf16 (pre-scaled)
    ushort_t* Kb    = Qb + E;                        // [b,h,s,d] bf16
    ushort_t* Vb    = Kb + E;                        // [b,h,d,s] bf16 (transposed)
    ushort_t* Hb    = Vb + E;                        // [4096][1024] bf16

    cvt_bf16<<<dim3(MROWS * D_MODEL / 1024), 256, 0, stream>>>(x, xb);
    cvt_transpose_w<<<dim3(32, 32, 4), 256, 0, stream>>>(Wq, Wk, Wv, Wo, WtQKV, WtO);
    gemm_mfma<<<dim3(24, 32), 256, 0, stream>>>(xb, WtQKV, bq, bk, bv,
                                                nullptr, Qb, Kb, Vb, 1);
    attn_mfma<<<dim3(SEQ / 64, BATCH * NHEADS), 256, 0, stream>>>(Qb, Kb, Vb, Hb);
    gemm_mfma<<<dim3(8, 32), 256, 0, stream>>>(Hb, WtO, bo, nullptr, nullptr,
                                               (float*)d_out, nullptr, nullptr, nullptr, 0);
}

// Round 5
// 204.855 us; speedup vs baseline: 6.0129x; 1.1080x over previous
//
#include <hip/hip_runtime.h>
#include <hip/hip_bf16.h>
#include <cmath>

#define D_MODEL 1024
#define NHEADS 16
#define HDIM 64
#define BATCH 2
#define SEQ 2048
#define MROWS (BATCH*SEQ)   // 4096
#define KDIM 1024

typedef unsigned short ushort_t;
typedef unsigned int uint32;
typedef __attribute__((ext_vector_type(8))) short short8;
typedef __attribute__((ext_vector_type(4))) float floatx4;

#define QSCALE 0.1803368801111204f   /* 0.125 * log2(e): scores land in exp2 domain */
#define EXP2F(x) __builtin_amdgcn_exp2f(x)

__device__ __forceinline__ ushort_t f2bf(float x) {
    union { float f; uint32 u; } v; v.f = x;
    uint32 r = v.u + 0x7FFFu + ((v.u >> 16) & 1u);
    return (ushort_t)(r >> 16);
}

__device__ __forceinline__ uint32 pkbf(float a, float b) {
    union { __hip_bfloat162 h2; uint32 u; } v;
    v.h2 = __float22bfloat162_rn(make_float2(a, b));
    return v.u;
}

__device__ __forceinline__ void glds16(const void* g, void* l) {
    __builtin_amdgcn_global_load_lds(
        (const __attribute__((address_space(1))) void*)g,
        (__attribute__((address_space(3))) void*)l, 16, 0, 0);
}

// ---------------- fp32 -> bf16 elementwise (x) ----------------
__global__ __launch_bounds__(256)
void cvt_bf16(const float* __restrict__ src, ushort_t* __restrict__ dst)
{
    size_t i = ((size_t)blockIdx.x * 256 + threadIdx.x) * 4;
    float4 v = *(const float4*)(src + i);
    uint2 o;
    o.x = pkbf(v.x, v.y);
    o.y = pkbf(v.z, v.w);
    *(uint2*)(dst + i) = o;
}

// ---------------- fp32 W[k][n] -> bf16 Wt[n][k] (transpose) ----------------
__global__ __launch_bounds__(256)
void cvt_transpose_w(const float* __restrict__ W0, const float* __restrict__ W1,
                     const float* __restrict__ W2, const float* __restrict__ W3,
                     ushort_t* __restrict__ WtQKV, ushort_t* __restrict__ WtO)
{
    __shared__ float tl[32][33];
    const int z = blockIdx.z;
    const float* W = (z == 0) ? W0 : (z == 1) ? W1 : (z == 2) ? W2 : W3;
    ushort_t* out = (z < 3) ? (WtQKV + (size_t)z * D_MODEL * KDIM) : WtO;
    const int k0 = blockIdx.x * 32, n0 = blockIdx.y * 32;
    const int tx = threadIdx.x & 31, ty = threadIdx.x >> 5;
    #pragma unroll
    for (int i = 0; i < 4; ++i)
        tl[ty + i * 8][tx] = W[(size_t)(k0 + ty + i * 8) * D_MODEL + n0 + tx];
    __syncthreads();
    #pragma unroll
    for (int i = 0; i < 4; ++i)
        out[(size_t)(n0 + ty + i * 8) * KDIM + k0 + tx] = f2bf(tl[tx][ty + i * 8]);
}

// ---------------- bf16 MFMA GEMM: C = A[4096,1024] * Bt^T + bias ----------------
// mode 0: fp32 C[m][n] (+bias) store.   mode 1: QKV epilogue:
//   Q -> bf16 [b,h,s,d] scaled by QSCALE; K -> bf16 [b,h,s,d]; V -> bf16 [b,h,d,s].
__global__ __launch_bounds__(256)
void gemm_mfma(const ushort_t* __restrict__ A, const ushort_t* __restrict__ Bt,
               const float* __restrict__ b0, const float* __restrict__ b1,
               const float* __restrict__ b2, float* __restrict__ Cf,
               ushort_t* __restrict__ Qb, ushort_t* __restrict__ Kb,
               ushort_t* __restrict__ Vb, int mode)
{
    __shared__ ushort_t As[128 * 64];   // 16 KB
    __shared__ ushort_t Bs[128 * 64];   // 16 KB

    const int tid = threadIdx.x;
    const int w = tid >> 6, lane = tid & 63;
    const int quad = lane >> 4, col = lane & 15;
    const int m0 = blockIdx.y * 128, n0 = blockIdx.x * 128;
    const int mbase = (w & 1) * 64, nbase = (w >> 1) * 64;

    floatx4 zero = {0.f, 0.f, 0.f, 0.f};
    floatx4 acc[4][4];
    #pragma unroll
    for (int i = 0; i < 4; ++i)
        #pragma unroll
        for (int j = 0; j < 4; ++j) acc[i][j] = zero;

    #pragma unroll 1
    for (int k0 = 0; k0 < KDIM; k0 += 64) {
        #pragma unroll
        for (int i = 0; i < 4; ++i) {
            int c = (w * 4 + i) * 64 + lane;
            int row = c >> 3;
            int kc = (c & 7) ^ (row & 7);
            glds16(A  + (size_t)(m0 + row) * KDIM + k0 + kc * 8, As + (w * 4 + i) * 512);
            glds16(Bt + (size_t)(n0 + row) * KDIM + k0 + kc * 8, Bs + (w * 4 + i) * 512);
        }
        __syncthreads();
        #pragma unroll
        for (int ks = 0; ks < 2; ++ks) {
            short8 af[4], bfr[4];
            const int kc = ks * 4 + quad;
            #pragma unroll
            for (int mt = 0; mt < 4; ++mt) {
                int r = mbase + mt * 16 + col;
                af[mt] = *(const short8*)(As + ((size_t)r * 8 + (kc ^ (r & 7))) * 8);
            }
            #pragma unroll
            for (int nt = 0; nt < 4; ++nt) {
                int r = nbase + nt * 16 + col;
                bfr[nt] = *(const short8*)(Bs + ((size_t)r * 8 + (kc ^ (r & 7))) * 8);
            }
            #pragma unroll
            for (int mt = 0; mt < 4; ++mt)
                #pragma unroll
                for (int nt = 0; nt < 4; ++nt)
                    acc[mt][nt] = __builtin_amdgcn_mfma_f32_16x16x32_bf16(
                        af[mt], bfr[nt], acc[mt][nt], 0, 0, 0);
        }
        __syncthreads();
    }

    if (mode == 0) {
        #pragma unroll
        for (int mt = 0; mt < 4; ++mt)
            #pragma unroll
            for (int nt = 0; nt < 4; ++nt) {
                int n = n0 + nbase + nt * 16 + col;
                float bb = b0[n];
                #pragma unroll
                for (int r = 0; r < 4; ++r) {
                    int m = m0 + mbase + mt * 16 + quad * 4 + r;
                    Cf[(size_t)m * D_MODEL + n] = acc[mt][nt][r] + bb;
                }
            }
    } else {
        const int which = n0 >> 10;
        const float* bp = (which == 0) ? b0 : (which == 1) ? b1 : b2;
        if (which < 2) {
            // Q (scaled) / K -> [b,h,s,d]
            ushort_t* outp = (which == 0) ? Qb : Kb;
            const float scl = (which == 0) ? QSCALE : 1.0f;
            #pragma unroll
            for (int mt = 0; mt < 4; ++mt)
                #pragma unroll
                for (int nt = 0; nt < 4; ++nt) {
                    int nn = (n0 + nbase + nt * 16 + col) & 1023;
                    float bb = bp[nn];
                    int h = nn >> 6, d = nn & 63;
                    #pragma unroll
                    for (int r = 0; r < 4; ++r) {
                        int m = m0 + mbase + mt * 16 + quad * 4 + r;
                        int b = m >> 11, s = m & 2047;
                        outp[((size_t)(b * NHEADS + h) * SEQ + s) * HDIM + d] =
                            f2bf((acc[mt][nt][r] + bb) * scl);
                    }
                }
        } else {
            // V -> [b,h,d,s] (transposed for attention PV), packed 8B stores
            #pragma unroll
            for (int mt = 0; mt < 4; ++mt)
                #pragma unroll
                for (int nt = 0; nt < 4; ++nt) {
                    int nn = (n0 + nbase + nt * 16 + col) & 1023;
                    float bb = bp[nn];
                    int h = nn >> 6, d = nn & 63;
                    int mb = m0 + mbase + mt * 16 + quad * 4;
                    int b = mb >> 11, s = mb & 2047;
                    uint2 pw;
                    pw.x = pkbf(acc[mt][nt][0] + bb, acc[mt][nt][1] + bb);
                    pw.y = pkbf(acc[mt][nt][2] + bb, acc[mt][nt][3] + bb);
                    *(uint2*)(Vb + ((size_t)(b * NHEADS + h) * HDIM + d) * SEQ + s) = pw;
                }
        }
    }
}

// ---------------- flash causal attention v3 ----------------
// Pair-balanced: block x processes q-tiles (31-x) then (x) -> uniform 33
// k-tile-steps per block; 512 blocks sustain ~2 blocks/CU with no tail.
// K/V staged via REGISTER prefetch: loads for tile t+1 issue after the
// post-staging barrier and fly during tile-t compute (global latency leaves
// the chain). ds_write_b128 lane-contiguous -> conflict-free.
// S^T = K.Q^T scheme (softmax stats: 15 local ops + 2 shfls per lane).
__global__ __launch_bounds__(256)
void attn_mfma(const ushort_t* __restrict__ Q, const ushort_t* __restrict__ K,
               const ushort_t* __restrict__ Vt, ushort_t* __restrict__ H)
{
    __shared__ ushort_t Qs[64 * 64];    // aliased as Ps after Q frags hoisted
    __shared__ ushort_t Ks[64 * 64];
    __shared__ ushort_t Vs[64 * 64];
    ushort_t* Ps = Qs;

    const int tid = threadIdx.x;
    const int w = tid >> 6, lane = tid & 63;
    const int quad = lane >> 4, col = lane & 15;
    const int bh = blockIdx.y;
    const size_t base = (size_t)bh * SEQ * HDIM;
    const ushort_t* Kb = K + base;
    const ushort_t* Vb = Vt + base;

    // staging chunks for this thread (2 K-chunks + 2 V-chunks per tile)
    const int c0 = (w * 2 + 0) * 64 + lane;
    const int c1 = (w * 2 + 1) * 64 + lane;
    const int r0 = c0 >> 3, o0 = ((c0 & 7) ^ (r0 & 7)) * 8;
    const int r1 = c1 >> 3, o1 = ((c1 & 7) ^ (r1 & 7)) * 8;

    const int qloc = w * 16 + col;       // this lane's q row (local) == Ps row
    const int rq = qloc;
    const floatx4 zero = {0.f, 0.f, 0.f, 0.f};
    const int b = bh >> 4, h = bh & 15;

    #pragma unroll 1
    for (int pi = 0; pi < 2; ++pi) {
        const int qt = pi ? (int)blockIdx.x : 31 - (int)blockIdx.x;
        const int q0 = qt * 64;

        __syncthreads();     // protect Qs/Ps from previous q-tile's readers
        #pragma unroll
        for (int i = 0; i < 2; ++i) {
            int c = (w * 2 + i) * 64 + lane;
            int row = c >> 3, kc = (c & 7) ^ (row & 7);
            glds16(Q + base + (size_t)(q0 + row) * HDIM + kc * 8, Qs + (w * 2 + i) * 512);
        }
        __syncthreads();
        short8 bq[2];
        #pragma unroll
        for (int ks = 0; ks < 2; ++ks) {
            int kc = ks * 4 + quad;
            bq[ks] = *(const short8*)(Qs + ((size_t)rq * 8 + (kc ^ (rq & 7))) * 8);
        }

        // preload k-tile 0 into regs
        uint4 kr0 = *(const uint4*)(Kb + (size_t)r0 * HDIM + o0);
        uint4 kr1 = *(const uint4*)(Kb + (size_t)r1 * HDIM + o1);
        uint4 vr0 = *(const uint4*)(Vb + (size_t)r0 * SEQ + o0);
        uint4 vr1 = *(const uint4*)(Vb + (size_t)r1 * SEQ + o1);

        floatx4 o[4];
        #pragma unroll
        for (int j = 0; j < 4; ++j) o[j] = zero;
        float mreg = -INFINITY, lreg = 0.f;

        #pragma unroll 1
        for (int t = 0; t <= qt; ++t) {
            __syncthreads();                     // all waves done reading Ks/Vs
            *(uint4*)(Ks + (size_t)c0 * 8) = kr0;
            *(uint4*)(Ks + (size_t)c1 * 8) = kr1;
            *(uint4*)(Vs + (size_t)c0 * 8) = vr0;
            *(uint4*)(Vs + (size_t)c1 * 8) = vr1;
            __syncthreads();                     // staged tile visible
            if (t < qt) {                        // prefetch t+1 during compute
                const int k0n = (t + 1) * 64;
                kr0 = *(const uint4*)(Kb + (size_t)(k0n + r0) * HDIM + o0);
                kr1 = *(const uint4*)(Kb + (size_t)(k0n + r1) * HDIM + o1);
                vr0 = *(const uint4*)(Vb + (size_t)r0 * SEQ + k0n + o0);
                vr1 = *(const uint4*)(Vb + (size_t)r1 * SEQ + k0n + o1);
            }

            // S^T[kpos][q]: sc[j] reg r -> kpos = j*16+quad*4+r, q = col
            floatx4 sc[4];
            #pragma unroll
            for (int j = 0; j < 4; ++j) sc[j] = zero;
            #pragma unroll
            for (int ks = 0; ks < 2; ++ks) {
                const int kc = ks * 4 + quad;
                #pragma unroll
                for (int j = 0; j < 4; ++j) {
                    int rk = j * 16 + col;
                    short8 ak = *(const short8*)(Ks + ((size_t)rk * 8 + (kc ^ (rk & 7))) * 8);
                    sc[j] = __builtin_amdgcn_mfma_f32_16x16x32_bf16(ak, bq[ks], sc[j], 0, 0, 0);
                }
            }

            // causal mask (diagonal tile only; wave-uniform branch)
            if (t == qt) {
                #pragma unroll
                for (int j = 0; j < 4; ++j)
                    #pragma unroll
                    for (int r = 0; r < 4; ++r)
                        if (j * 16 + quad * 4 + r > qloc) sc[j][r] = -INFINITY;
            }

            // online softmax: local max/sum over 16 regs + 2 shfls across quads
            float mx = -INFINITY;
            #pragma unroll
            for (int j = 0; j < 4; ++j)
                mx = fmaxf(mx, fmaxf(fmaxf(sc[j][0], sc[j][1]), fmaxf(sc[j][2], sc[j][3])));
            mx = fmaxf(mx, __shfl_xor(mx, 16));
            mx = fmaxf(mx, __shfl_xor(mx, 32));
            float mn = fmaxf(mreg, mx);
            float alpha = EXP2F(mreg - mn);
            mreg = mn;

            float ls = 0.f;
            #pragma unroll
            for (int j = 0; j < 4; ++j) {
                float p0 = EXP2F(sc[j][0] - mn);
                float p1 = EXP2F(sc[j][1] - mn);
                float p2 = EXP2F(sc[j][2] - mn);
                float p3 = EXP2F(sc[j][3] - mn);
                ls += (p0 + p1) + (p2 + p3);
                uint2 pw;
                pw.x = pkbf(p0, p1);
                pw.y = pkbf(p2, p3);
                int c = 2 * j + (quad >> 1);
                *(uint2*)(Ps + ((size_t)rq * 8 + (c ^ (rq & 7))) * 8 + (quad & 1) * 4) = pw;
            }
            ls += __shfl_xor(ls, 16);
            ls += __shfl_xor(ls, 32);
            lreg = lreg * alpha + ls;
            #pragma unroll
            for (int j = 0; j < 4; ++j) {
                o[j][0] *= alpha; o[j][1] *= alpha; o[j][2] *= alpha; o[j][3] *= alpha;
            }

            // O^T += V^T . P^T : A-frag rows = d (Vs), B-frag rows = q (Ps, own wave)
            #pragma unroll
            for (int ks = 0; ks < 2; ++ks) {
                const int kc = ks * 4 + quad;
                short8 bp = *(const short8*)(Ps + ((size_t)rq * 8 + (kc ^ (rq & 7))) * 8);
                #pragma unroll
                for (int j = 0; j < 4; ++j) {
                    int rv = j * 16 + col;
                    short8 av = *(const short8*)(Vs + ((size_t)rv * 8 + (kc ^ (rv & 7))) * 8);
                    o[j] = __builtin_amdgcn_mfma_f32_16x16x32_bf16(av, bp, o[j], 0, 0, 0);
                }
            }
        }

        // epilogue: lane owns q row s = q0+qloc, d = j*16+quad*4+r; H[b,s,h*64+d]
        const float linv = 1.f / lreg;
        const size_t rowb = ((size_t)(b * SEQ + q0 + qloc)) * D_MODEL + h * HDIM;
        #pragma unroll
        for (int j = 0; j < 4; ++j) {
            uint2 pw;
            pw.x = pkbf(o[j][0] * linv, o[j][1] * linv);
            pw.y = pkbf(o[j][2] * linv, o[j][3] * linv);
            *(uint2*)(H + rowb + j * 16 + quad * 4) = pw;
        }
    }
}

extern "C" void kernel_launch(void* const* d_in, const int* in_sizes, int n_in,
                              void* d_out, int out_size, void* d_ws, size_t ws_size,
                              hipStream_t stream)
{
    (void)in_sizes; (void)n_in; (void)out_size; (void)ws_size;
    const float* x  = (const float*)d_in[0];
    const float* Wq = (const float*)d_in[1];
    const float* bq = (const float*)d_in[2];
    const float* Wk = (const float*)d_in[3];
    const float* bk = (const float*)d_in[4];
    const float* Wv = (const float*)d_in[5];
    const float* bv = (const float*)d_in[6];
    const float* Wo = (const float*)d_in[7];
    const float* bo = (const float*)d_in[8];

    const size_t E = (size_t)MROWS * D_MODEL;
    ushort_t* xb    = (ushort_t*)d_ws;               // [4096][1024] bf16
    ushort_t* WtQKV = xb + E;                        // [3072][1024] bf16
    ushort_t* WtO   = WtQKV + 3 * (size_t)D_MODEL * KDIM;
    ushort_t* Qb    = WtO + (size_t)D_MODEL * KDIM;  // [b,h,s,d] bf16 (pre-scaled)
    ushort_t* Kb    = Qb + E;                        // [b,h,s,d] bf16
    ushort_t* Vb    = Kb + E;                        // [b,h,d,s] bf16 (transposed)
    ushort_t* Hb    = Vb + E;                        // [4096][1024] bf16

    cvt_bf16<<<dim3(MROWS * D_MODEL / 1024), 256, 0, stream>>>(x, xb);
    cvt_transpose_w<<<dim3(32, 32, 4), 256, 0, stream>>>(Wq, Wk, Wv, Wo, WtQKV, WtO);
    gemm_mfma<<<dim3(24, 32), 256, 0, stream>>>(xb, WtQKV, bq, bk, bv,
                                                nullptr, Qb, Kb, Vb, 1);
    attn_mfma<<<dim3(16, BATCH * NHEADS), 256, 0, stream>>>(Qb, Kb, Vb, Hb);
    gemm_mfma<<<dim3(8, 32), 256, 0, stream>>>(Hb, WtO, bo, nullptr, nullptr,
                                               (float*)d_out, nullptr, nullptr, nullptr, 0);
}